// Round 1
// baseline (66.202 us; speedup 1.0000x reference)
//
#include <hip/hip_runtime.h>
#include <hip/hip_bf16.h>

// FillPolygon: B=4, H=W=256, N_PTS=128.
// out[b, i, j] = relu(1 + r_rbf(b, ttm(i,j)) - rm(i,j))
// where ttm = max(atan2(j-128, i-128), 0), rm = sqrt((i-128)^2 + (j-128)^2),
// r_rbf = sum_jj e_jj * r1_jj / sum_jj e_jj over 384 angle copies,
// e = exp(-100 * min((tt1 - ttm)^2, 1)).
// Scale-invariance of num/den lets us add +50 inside the exponent to stay
// out of denormal range: e' = exp2(d * C1 + C2), C1=-100*log2(e), C2=50*log2(e).

#define TWO_PI_F 6.283185307179586f
#define C1_EXP  (-144.26950408889634f)   // -100 * log2(e)
#define C2_EXP  (72.13475204444817f)     //  +50 * log2(e)

static __device__ __forceinline__ float fast_exp2(float x) {
#if __has_builtin(__builtin_amdgcn_exp2f)
    return __builtin_amdgcn_exp2f(x);
#else
    return exp2f(x);
#endif
}

// ---- Kernel 1: per-batch point prep + rbf0 (value of r_rbf at ttm == 0) ----
// grid: B blocks, 384 threads.
__global__ __launch_bounds__(384) void fp_prep_kernel(
        const float* __restrict__ in,   // (B, 128, 2)
        float2* __restrict__ tr,        // (B, 384) interleaved (tt1, r1)
        float* __restrict__ rbf0)       // (B,)
{
    __shared__ float2 s[384];
    __shared__ float pn[6], pd[6];
    const int b = blockIdx.x;
    const int tid = threadIdx.x;

    if (tid < 128) {
        float x = in[b * 256 + tid * 2 + 0];
        float y = in[b * 256 + tid * 2 + 1];
        float dx = x - 128.0f, dy = y - 128.0f;
        float r = sqrtf(dx * dx + dy * dy);
        float t = fmaxf(atan2f(dy, dx), 0.0f);  // fix_radians == relu here
        s[tid]       = make_float2(t - TWO_PI_F, r);
        s[tid + 128] = make_float2(t,            r);
        s[tid + 256] = make_float2(t + TWO_PI_F, r);
    }
    __syncthreads();

    tr[b * 384 + tid] = s[tid];

    // rbf0: r_rbf evaluated at ttm = 0 (shared by every gy<0 pixel)
    float2 v = s[tid];
    float d  = fminf(v.x * v.x, 1.0f);
    float e  = fast_exp2(fmaf(d, C1_EXP, C2_EXP));
    float num = e * v.y;
    float den = e;
    #pragma unroll
    for (int off = 32; off > 0; off >>= 1) {
        num += __shfl_down(num, off);
        den += __shfl_down(den, off);
    }
    if ((tid & 63) == 0) { pn[tid >> 6] = num; pd[tid >> 6] = den; }
    __syncthreads();
    if (tid == 0) {
        float n = 0.0f, dd = 0.0f;
        #pragma unroll
        for (int w = 0; w < 6; ++w) { n += pn[w]; dd += pd[w]; }
        rbf0[b] = n / dd;
    }
}

// ---- Kernel 2: per-pixel RBF average ----
// grid: B*256 blocks, 256 threads. bid>>8 = b, bid&255 = i (gx), tid = j (gy).
__global__ __launch_bounds__(256) void fp_main_kernel(
        const float2* __restrict__ tr,
        const float* __restrict__ rbf0,
        float* __restrict__ out)
{
    __shared__ float2 s[384];
    const int tid = threadIdx.x;
    const int bid = blockIdx.x;
    const int b = bid >> 8;
    const int i = bid & 255;

    const float2* trb = tr + b * 384;
    s[tid] = trb[tid];
    if (tid < 128) s[tid + 256] = trb[tid + 256];

    float gx = (float)i   - 128.0f;
    float gy = (float)tid - 128.0f;
    float rm  = sqrtf(gx * gx + gy * gy);
    float ttm = fmaxf(atan2f(gy, gx), 0.0f);
    __syncthreads();

    float rbf;
    if (__all(ttm == 0.0f)) {
        // whole wave shares the precomputed ttm==0 answer (half of all waves)
        rbf = rbf0[b];
    } else {
        float num = 0.0f, den = 0.0f;
        #pragma unroll 8
        for (int jj = 0; jj < 384; ++jj) {
            float2 v = s[jj];
            float dt = v.x - ttm;
            float d  = fminf(dt * dt, 1.0f);
            float e  = fast_exp2(fmaf(d, C1_EXP, C2_EXP));
            num = fmaf(e, v.y, num);
            den += e;
        }
        rbf = num / den;
    }

    out[bid * 256 + tid] = fmaxf(1.0f + rbf - rm, 0.0f);
}

extern "C" void kernel_launch(void* const* d_in, const int* in_sizes, int n_in,
                              void* d_out, int out_size, void* d_ws, size_t ws_size,
                              hipStream_t stream) {
    const float* in = (const float*)d_in[0];
    float* out = (float*)d_out;

    // workspace layout: float2 tr[4][384] (12288 B) then float rbf0[4]
    float2* tr  = (float2*)d_ws;
    float* rbf0 = (float*)((char*)d_ws + 4 * 384 * sizeof(float2));

    fp_prep_kernel<<<4, 384, 0, stream>>>(in, tr, rbf0);
    fp_main_kernel<<<1024, 256, 0, stream>>>(tr, rbf0, out);
}

// Round 2
// 57.094 us; speedup vs baseline: 1.1595x; 1.1595x over previous
//
#include <hip/hip_runtime.h>
#include <hip/hip_bf16.h>

// FillPolygon: B=4, H=W=256, N_PTS=128. Single fused kernel.
//
// out[b,i,j] = relu(1 + r_rbf(b, ttm) - rm),  ttm = relu(atan2(gy,gx)) in [0,pi],
// r_rbf = sum_jj e*r1 / sum_jj e over 3x128 angle copies, e = exp(-100*min(dt^2,1)).
//
// Key facts used:
//  * fix_radians == relu on atan2's range (-pi, pi].
//  * Point angles t and pixel angles ttm both lie in [0, pi], so the +-2pi
//    copies always have |dt| >= pi > 1 -> d clamps to exactly 1. Their
//    contribution is the closed-form floor: num += F*2*sumR, den += F*256.
//    Loop is only the 128 center copies.
//  * num/den is scale-invariant: multiply both by e^{50} to keep every term
//    in normal fp32 range. e' = exp2(d*C1 + C2), floor F = e^{-50}.

#define C1_EXP  (-144.26950408889634f)   // -100 * log2(e)
#define C2_EXP  (72.13475204444817f)     //  +50 * log2(e)
#define FLOOR_E (1.9287498479639178e-22f) // exp(-50) = 2^(C1+C2)

static __device__ __forceinline__ float fast_exp2(float x) {
#if __has_builtin(__builtin_amdgcn_exp2f)
    return __builtin_amdgcn_exp2f(x);
#else
    return exp2f(x);
#endif
}

// grid: B*256 blocks, 256 threads. bid>>8 = b, bid&255 = i (x/gx), tid = j (y/gy).
__global__ __launch_bounds__(256) void fp_fused_kernel(
        const float* __restrict__ in,   // (B, 128, 2)
        float* __restrict__ out)        // (B, 256, 256)
{
    __shared__ float2 s_tr[128];        // (t, r) per point, center copy
    __shared__ float  s_part[2][3];     // per-wave partials: {e*r, e, r}
    const int tid = threadIdx.x;
    const int bid = blockIdx.x;
    const int b = bid >> 8;
    const int i = bid & 255;

    // ---- prep: 128 points, computed redundantly per block (cheap) ----
    if (tid < 128) {
        float2 p = ((const float2*)in)[b * 128 + tid];
        float dx = p.x - 128.0f, dy = p.y - 128.0f;
        float r = sqrtf(dx * dx + dy * dy);
        float t = fmaxf(atan2f(dy, dx), 0.0f);   // fix_radians == relu
        s_tr[tid] = make_float2(t, r);
        // partials for the shared ttm==0 answer (all gy<0 pixels)
        float d0 = fminf(t * t, 1.0f);
        float e0 = fast_exp2(fmaf(d0, C1_EXP, C2_EXP));
        float er = e0 * r, se = e0, sr = r;
        #pragma unroll
        for (int off = 32; off > 0; off >>= 1) {
            er += __shfl_down(er, off);
            se += __shfl_down(se, off);
            sr += __shfl_down(sr, off);
        }
        if ((tid & 63) == 0) {
            s_part[tid >> 6][0] = er;
            s_part[tid >> 6][1] = se;
            s_part[tid >> 6][2] = sr;
        }
    }
    __syncthreads();

    const float sumER = s_part[0][0] + s_part[1][0];
    const float sumE  = s_part[0][1] + s_part[1][1];
    const float sumR  = s_part[0][2] + s_part[1][2];
    const float floorNum = 2.0f * sumR * FLOOR_E;   // 256 clamped copies
    const float floorDen = 256.0f * FLOOR_E;

    const float gx = (float)i   - 128.0f;
    const float gy = (float)tid - 128.0f;
    const float rm  = sqrtf(gx * gx + gy * gy);
    const float ttm = fmaxf(atan2f(gy, gx), 0.0f);

    float rbf;
    if (__all(ttm == 0.0f)) {
        // whole wave (all gy<0) shares the ttm==0 answer
        rbf = (sumER + floorNum) / (sumE + floorDen);
    } else {
        float num = floorNum, den = floorDen;
        #pragma unroll 8
        for (int jj = 0; jj < 128; ++jj) {
            float2 v = s_tr[jj];
            float dt = v.x - ttm;
            float d  = fminf(dt * dt, 1.0f);
            float e  = fast_exp2(fmaf(d, C1_EXP, C2_EXP));
            num = fmaf(e, v.y, num);
            den += e;
        }
        rbf = num / den;
    }

    out[bid * 256 + tid] = fmaxf(1.0f + rbf - rm, 0.0f);
}

extern "C" void kernel_launch(void* const* d_in, const int* in_sizes, int n_in,
                              void* d_out, int out_size, void* d_ws, size_t ws_size,
                              hipStream_t stream) {
    const float* in = (const float*)d_in[0];
    float* out = (float*)d_out;
    fp_fused_kernel<<<1024, 256, 0, stream>>>(in, out);
}